// Round 2
// baseline (28061.328 us; speedup 1.0000x reference)
//
#include <hip/hip_runtime.h>

// Bisection probe: literal, fully-sequential port of the reference recurrence.
// 1 thread = 1 band (Z=200). Strict reference fp order:
//   - no FMA contraction (__f*_rn intrinsics + fp contract(off))
//   - 18-term dot accumulated strictly left-to-right
//   - floor(log2|d|) exact via exponent field; damp exact power of 2
// LDS rolling row buffer (lane-private, +1 pad) supplies N/NW/NE; the 15
// spectral taps read global memory (13 MB image is cache-resident).

#define XD 128
#define YD 128
#define TP (XD * YD)
#define NBANDS 200

__global__ __launch_bounds__(64, 1)
void spectral_scan_literal(const float* __restrict__ img, float* __restrict__ out) {
#pragma clang fp contract(off)
    __shared__ float prow[64][XD + 1];   // lane-private previous-row buffer

    const int lane = threadIdx.x;
    const int z = blockIdx.x * 64 + lane;
    if (z >= NBANDS) return;             // no barriers used -> safe early exit

    const float* base = img + (size_t)z * TP;
    float* ob = out + (size_t)z * TP;

    float w[18];
    #pragma unroll
    for (int i = 0; i < 18; ++i) w[i] = 0.0f;
    const bool du = (z >= 1);

    for (int y = 0; y < YD; ++y) {
        float sprev = 0.0f, Nprev = 0.0f;
        const float* row = base + y * XD;
        for (int x = 0; x < XD; ++x) {
            float s = row[x];
            float N = 0.0f, NE = 0.0f;
            if (y > 0) {
                N  = prow[lane][x];
                NE = (x < XD - 1) ? prow[lane][x + 1] : 0.0f;
            }
            float W  = (x > 0) ? sprev : 0.0f;
            float NW = (y > 0 && x > 0) ? Nprev : 0.0f;

            float sigma;
            if (y > 0) {
                if (x == 0)           sigma = 2.0f * __fadd_rn(N, NE);
                else if (x == XD - 1) sigma = 2.0f * __fadd_rn(W, NW);
                else sigma = __fadd_rn(__fadd_rn(__fadd_rn(NW, NE), W), N);
            } else {
                sigma = (x > 0) ? 4.0f * W : 0.0f;
            }

            float d[18];
            d[0] = __fsub_rn(4.0f * N,  sigma);
            d[1] = __fsub_rn(4.0f * W,  sigma);
            d[2] = __fsub_rn(4.0f * NW, sigma);
            #pragma unroll
            for (int p = 0; p < 15; ++p) {
                int zp = z - 15 + p;
                float pv = (zp >= 0) ? img[(size_t)zp * TP + y * XD + x] : 0.0f;
                d[3 + p] = (zp >= 0) ? __fsub_rn(4.0f * pv, sigma) : 0.0f;
            }

            // strict left-to-right 18-term dot
            float acc = __fmul_rn(w[0], d[0]);
            #pragma unroll
            for (int i = 1; i < 18; ++i)
                acc = __fadd_rn(acc, __fmul_rn(w[i], d[i]));

            float praw = __fadd_rn(__fmul_rn(sigma, 0.25f), acc);
            float pred = fminf(32767.0f, fmaxf(-32768.0f, praw));
            ob[y * XD + x] = pred;

            float e = __fsub_rn(s, pred);
            if (du) {
                float e16 = __fmul_rn(0.0625f, e);      // 2^-4 * e (exact)
                #pragma unroll
                for (int c = 0; c < 4; ++c) {
                    float dc = d[c];
                    float ad = fabsf(dc);
                    int Ei = (__float_as_int(dc) >> 23) & 255;
                    int t = Ei - 133;                    // max(0, floor(log2|d|)-6)
                    t = t < 0 ? 0 : t;
                    float damp = __int_as_float((127 - t) << 23);  // 2^-t exact
                    float upd = __fmul_rn(__fmul_rn(e16, dc), damp);
                    upd = (ad > 0.0f) ? upd : 0.0f;
                    w[c] = fminf(2.0f, fmaxf(-2.0f, __fadd_rn(w[c], upd)));
                }
                float us = __fmul_rn(e16, 0.1f);
                #pragma unroll
                for (int c = 4; c < 18; ++c)
                    w[c] = fminf(2.0f, fmaxf(-2.0f, __fadd_rn(w[c], us)));
            }

            if (x > 0) prow[lane][x - 1] = sprev;  // safe: [x-1] no longer read
            Nprev = N;
            sprev = s;
        }
        prow[lane][XD - 1] = sprev;                // s(y, 127) completes the row
    }
}

extern "C" void kernel_launch(void* const* d_in, const int* in_sizes, int n_in,
                              void* d_out, int out_size, void* d_ws, size_t ws_size,
                              hipStream_t stream) {
    (void)in_sizes; (void)n_in; (void)d_ws; (void)ws_size; (void)out_size;
    const float* img = (const float*)d_in[0];
    float* out = (float*)d_out;
    spectral_scan_literal<<<(NBANDS + 63) / 64, 64, 0, stream>>>(img, out);
}

// Round 4
// 2546.449 us; speedup vs baseline: 11.0198x; 11.0198x over previous
//
#include <hip/hip_runtime.h>

// Producer/consumer pipeline with BIT-EXACT round-2 arithmetic in the scan.
// r2 (strict left-assoc __f*_rn ops) passed at absmax 42; r1's reassociated
// math decorrelated the chaotic recurrence. This keeps r2's op sequence and
// fixes the memory system:
//  - producer wave stages image rows into LDS and precomputes per-step
//    records: d[0..17], k[0..3] (= d * 2^-t, exact pow2 scale), sigma/4, s
//  - consumer wave (8 lanes = 8 bands) runs only the serial chain from LDS
// 25 blocks x 128 threads; 512 phases of 32 pixels; 1 barrier/phase.
// (r3 failed to compile: macro token-pasting n##0.x lexed 0.x as a pp-number.
//  Replaced with a Rec struct + lambdas; same intended codegen.)

#define XD 128
#define YD 128
#define TP (XD * XD)
#define NREC 772   // 32 px * 24 floats + 4 pad

struct Rec { float4 a, b, c, d, e, f; };

__global__ __launch_bounds__(128, 1)
void spectral_pipe(const float* __restrict__ img, float* __restrict__ out) {
#pragma clang fp contract(off)
    __shared__ __align__(16) float cur[23][132];   // row y, bands b0-15..b0+7
    __shared__ __align__(16) float prevS[8][132];  // row y-1, scan bands
    __shared__ __align__(16) float rec[2][8][NREC];

    const int tid = threadIdx.x;
    const int wv  = tid >> 6;
    const int ln  = tid & 63;
    const int b0  = blockIdx.x * 8;

    auto rowload = [&](int y) {
        for (int q = ln; q < 23 * 32; q += 64) {
            int j = q >> 5, r = q & 31;
            int band = b0 - 15 + j;
            float4 v = make_float4(0.f, 0.f, 0.f, 0.f);
            if (band >= 0)
                v = ((const float4*)(img + (size_t)band * TP + (size_t)y * XD))[r];
            *(float4*)&cur[j][r << 2] = v;
        }
    };
    auto rowcopy = [&]() {
        for (int q = ln; q < 8 * 32; q += 64) {
            int b = q >> 5, r = q & 31;
            *(float4*)&prevS[b][r << 2] = *(const float4*)&cur[15 + b][r << 2];
        }
    };
    auto produce = [&](int phN) {
        int y = phN >> 2, x0 = (phN & 3) << 5, cb = phN & 1;
        for (int it = ln; it < 256; it += 64) {
            int b = it >> 5, i = it & 31, x = x0 + i;
            int z = b0 + b;
            const float* cr = cur[15 + b];
            const float* pr = prevS[b];
            float s = cr[x];
            float W = (x > 0) ? cr[x - 1] : 0.0f;
            float N = 0.0f, NW = 0.0f, NE = 0.0f;
            if (y > 0) {
                N  = pr[x];
                NE = (x < XD - 1) ? pr[x + 1] : 0.0f;
                NW = (x > 0) ? pr[x - 1] : 0.0f;
            }
            float sigma;
            if (y > 0) {
                if (x == 0)           sigma = 2.0f * __fadd_rn(N, NE);
                else if (x == XD - 1) sigma = 2.0f * __fadd_rn(W, NW);
                else sigma = __fadd_rn(__fadd_rn(__fadd_rn(NW, NE), W), N);
            } else {
                sigma = (x > 0) ? 4.0f * W : 0.0f;
            }
            float d[18];
            d[0] = __fsub_rn(4.0f * N,  sigma);
            d[1] = __fsub_rn(4.0f * W,  sigma);
            d[2] = __fsub_rn(4.0f * NW, sigma);
            #pragma unroll
            for (int p = 0; p < 15; ++p) {
                int zp = z - 15 + p;
                d[3 + p] = (zp >= 0) ? __fsub_rn(4.0f * cur[b + p][x], sigma) : 0.0f;
            }
            float k[4];
            #pragma unroll
            for (int c = 0; c < 4; ++c) {
                int E = (__float_as_int(d[c]) >> 23) & 255;
                int t = E - 133;                       // max(0, floor(log2|d|)-6)
                t = t < 0 ? 0 : t;
                float damp = __int_as_float((127 - t) << 23);  // 2^-t exact
                k[c] = (z >= 1) ? __fmul_rn(d[c], damp) : 0.0f;
            }
            float* rp = &rec[cb][b][i * 24];
            ((float4*)rp)[0] = make_float4(d[0],  d[1],  d[2],  d[3]);
            ((float4*)rp)[1] = make_float4(d[4],  d[5],  d[6],  d[7]);
            ((float4*)rp)[2] = make_float4(d[8],  d[9],  d[10], d[11]);
            ((float4*)rp)[3] = make_float4(d[12], d[13], d[14], d[15]);
            ((float4*)rp)[4] = make_float4(d[16], d[17], __fmul_rn(sigma, 0.25f), s);
            ((float4*)rp)[5] = make_float4(k[0],  k[1],  k[2],  k[3]);
        }
    };

    if (wv == 1) {
        rowload(0);
        asm volatile("s_waitcnt lgkmcnt(0)" ::: "memory");
        produce(0);
    }
    __syncthreads();

    float w0 = 0.f, w1 = 0.f, w2 = 0.f, w3 = 0.f, ws = 0.f;
    const int z = b0 + ln;
    const float uk = (z == 0) ? 0.0f : 0.1f;
    float* op = out + (size_t)z * TP;

    for (int ph = 0; ph < 512; ++ph) {
        if (wv == 1) {
            if (ph < 511) {
                int phN = ph + 1;
                if ((phN & 3) == 0) {
                    rowcopy();
                    asm volatile("s_waitcnt lgkmcnt(0)" ::: "memory");
                    rowload(phN >> 2);
                    asm volatile("s_waitcnt lgkmcnt(0)" ::: "memory");
                }
                produce(phN);
            }
        } else if (ln < 8) {
            const float* sb = &rec[ph & 1][ln][0];
            float* o = op + ph * 32;

            auto ld = [&](int px) -> Rec {
                Rec r;
                const float4* p = (const float4*)(sb + px * 24);
                r.a = p[0]; r.b = p[1]; r.c = p[2];
                r.d = p[3]; r.e = p[4]; r.f = p[5];
                return r;
            };
            // r2-exact per-step arithmetic (strict left-assoc dot, same clamps)
            auto step = [&](const Rec& r, float* po) {
                float acc = __fmul_rn(w0, r.a.x);
                acc = __fadd_rn(acc, __fmul_rn(w1, r.a.y));
                acc = __fadd_rn(acc, __fmul_rn(w2, r.a.z));
                acc = __fadd_rn(acc, __fmul_rn(w3, r.a.w));
                acc = __fadd_rn(acc, __fmul_rn(ws, r.b.x));
                acc = __fadd_rn(acc, __fmul_rn(ws, r.b.y));
                acc = __fadd_rn(acc, __fmul_rn(ws, r.b.z));
                acc = __fadd_rn(acc, __fmul_rn(ws, r.b.w));
                acc = __fadd_rn(acc, __fmul_rn(ws, r.c.x));
                acc = __fadd_rn(acc, __fmul_rn(ws, r.c.y));
                acc = __fadd_rn(acc, __fmul_rn(ws, r.c.z));
                acc = __fadd_rn(acc, __fmul_rn(ws, r.c.w));
                acc = __fadd_rn(acc, __fmul_rn(ws, r.d.x));
                acc = __fadd_rn(acc, __fmul_rn(ws, r.d.y));
                acc = __fadd_rn(acc, __fmul_rn(ws, r.d.z));
                acc = __fadd_rn(acc, __fmul_rn(ws, r.d.w));
                acc = __fadd_rn(acc, __fmul_rn(ws, r.e.x));
                acc = __fadd_rn(acc, __fmul_rn(ws, r.e.y));
                float praw = __fadd_rn(r.e.z, acc);
                float pred = fminf(32767.0f, fmaxf(-32768.0f, praw));
                *po = pred;
                float e = __fsub_rn(r.e.w, pred);
                float e16 = __fmul_rn(0.0625f, e);
                w0 = fminf(2.0f, fmaxf(-2.0f, __fadd_rn(w0, __fmul_rn(e16, r.f.x))));
                w1 = fminf(2.0f, fmaxf(-2.0f, __fadd_rn(w1, __fmul_rn(e16, r.f.y))));
                w2 = fminf(2.0f, fmaxf(-2.0f, __fadd_rn(w2, __fmul_rn(e16, r.f.z))));
                w3 = fminf(2.0f, fmaxf(-2.0f, __fadd_rn(w3, __fmul_rn(e16, r.f.w))));
                ws = fminf(2.0f, fmaxf(-2.0f, __fadd_rn(ws, __fmul_rn(e16, uk))));
            };

            Rec P = ld(0), Q = ld(1);
            #pragma unroll 1
            for (int g = 0; g < 8; ++g) {
                int base = 4 * g;
                Rec R = ld(base + 2), S = ld(base + 3);
                step(P, o + base);
                step(Q, o + base + 1);
                if (g < 7) { P = ld(base + 4); Q = ld(base + 5); }
                step(R, o + base + 2);
                step(S, o + base + 3);
            }
        }
        __syncthreads();
    }
}

extern "C" void kernel_launch(void* const* d_in, const int* in_sizes, int n_in,
                              void* d_out, int out_size, void* d_ws, size_t ws_size,
                              hipStream_t stream) {
    (void)in_sizes; (void)n_in; (void)d_ws; (void)ws_size; (void)out_size;
    const float* img = (const float*)d_in[0];
    float* out = (float*)d_out;
    spectral_pipe<<<25, 128, 0, stream>>>(img, out);
}